// Round 7
// baseline (234.384 us; speedup 1.0000x reference)
//
#include <hip/hip_runtime.h>
#include <hip/hip_bf16.h>

typedef __attribute__((ext_vector_type(8))) short s8v;   // 8 x bf16 raw (4 VGPRs)
typedef __attribute__((ext_vector_type(4))) float f4v;   // MFMA accumulator

__device__ __forceinline__ ushort f2bf(float f) {
    union { float f; unsigned u; } cv; cv.f = f;
    unsigned u = cv.u;
    unsigned lsb = (u >> 16) & 1u;
    u += 0x7fffu + lsb;          // RNE round to bf16
    return (ushort)(u >> 16);
}

// async global->LDS, 16B per lane; LDS dest is wave-uniform base + lane*16
typedef __attribute__((address_space(1))) void gvoid;
typedef __attribute__((address_space(3))) void lvoid;
__device__ __forceinline__ void gl_lds16(const ushort* g, ushort* l) {
    __builtin_amdgcn_global_load_lds((gvoid*)g, (lvoid*)l, 16, 0, 0);
}

// ---------------- cast fp32 -> bf16 (vectorized) ----------------
__global__ void cast_bf16_kernel(const float* __restrict__ in, ushort* __restrict__ out, int n4) {
    int i = blockIdx.x * blockDim.x + threadIdx.x;
    if (i >= n4) return;
    float4 v = reinterpret_cast<const float4*>(in)[i];
    ushort4 o;
    o.x = f2bf(v.x); o.y = f2bf(v.y); o.z = f2bf(v.z); o.w = f2bf(v.w);
    reinterpret_cast<ushort4*>(out)[i] = o;
}

// ---------------- transpose + cast: in[R][C] fp32 -> out[C][R] bf16 ----------------
__global__ void transpose_cast_kernel(const float* __restrict__ in, ushort* __restrict__ out,
                                      int R, int C) {
    __shared__ float tile[32][33];
    int c0 = blockIdx.x * 32, r0 = blockIdx.y * 32;
    int tx = threadIdx.x & 31, ty = threadIdx.x >> 5;
    #pragma unroll
    for (int i = 0; i < 32; i += 8)
        tile[ty + i][tx] = in[(size_t)(r0 + ty + i) * C + c0 + tx];
    __syncthreads();
    #pragma unroll
    for (int i = 0; i < 32; i += 8)
        out[(size_t)(c0 + ty + i) * R + r0 + tx] = f2bf(tile[tx][ty + i]);
}

// ---------------- V transpose: qkv V part -> Vt[b*16+h][64 d][T s] bf16 ----------------
__global__ __launch_bounds__(256) void vtrans_kernel(
    const ushort* __restrict__ qkv, ushort* __restrict__ vt_g, int T)
{
    __shared__ ushort tile[64][72];
    const int sb = blockIdx.x * 64, bh = blockIdx.y;
    const int b = bh >> 4, h = bh & 15;
    const int t = threadIdx.x;
    const int r0 = t >> 3, c0 = (t & 7) * 8;
    const ushort* vsrc = qkv + (size_t)b * T * 3072 + 2048 + h * 64;
    *(s8v*)&tile[r0][c0]      = *(const s8v*)(vsrc + (size_t)(sb + r0) * 3072 + c0);
    *(s8v*)&tile[32 + r0][c0] = *(const s8v*)(vsrc + (size_t)(sb + 32 + r0) * 3072 + c0);
    __syncthreads();
    ushort* vdst = vt_g + (size_t)bh * 64 * T;
    s8v o0, o1;
    #pragma unroll
    for (int j = 0; j < 8; j++) {
        o0[j] = (short)tile[c0 + j][r0];
        o1[j] = (short)tile[c0 + j][32 + r0];
    }
    *(s8v*)(vdst + (size_t)r0 * T + sb + c0)        = o0;
    *(s8v*)(vdst + (size_t)(32 + r0) * T + sb + c0) = o1;
}

// ---------------- bf16 MFMA GEMM (m97 structure): C = A * Bt^T + bias ----------------
template <bool OUT_BF16>
__global__ __launch_bounds__(256) void gemm_bt_kernel(
    const ushort* __restrict__ A, const ushort* __restrict__ Bt,
    const float* __restrict__ bias, void* __restrict__ Cout,
    int M, int N, int K)
{
    __shared__ ushort As[128][64];   // linear (global_load_lds requires contiguous dest)
    __shared__ ushort Bs[128][64];
    const int t = threadIdx.x;
    const int m0 = blockIdx.y * 128, n0 = blockIdx.x * 128;
    const int wave = t >> 6, lane = t & 63;
    const int lr = lane & 15, lg = lane >> 4;
    const int wm = (wave >> 1) * 64, wn = (wave & 1) * 64;
    const int lrow = lane >> 3;
    const int lcol = (lane & 7) * 8;

    f4v acc[4][4];
    #pragma unroll
    for (int i = 0; i < 4; i++)
        #pragma unroll
        for (int j = 0; j < 4; j++)
            acc[i][j] = (f4v){0.f, 0.f, 0.f, 0.f};

    for (int k0 = 0; k0 < K; k0 += 64) {
        __syncthreads();
        #pragma unroll
        for (int i = 0; i < 4; i++) {
            int j = wave * 4 + i;
            int row = j * 8 + lrow;
            gl_lds16(A  + (size_t)(m0 + row) * K + k0 + lcol, &As[j * 8][0]);
            gl_lds16(Bt + (size_t)(n0 + row) * K + k0 + lcol, &Bs[j * 8][0]);
        }
        __syncthreads();
        #pragma unroll
        for (int ks = 0; ks < 64; ks += 32) {
            s8v af[4], bfr[4];
            #pragma unroll
            for (int mb = 0; mb < 4; mb++)
                af[mb] = *reinterpret_cast<const s8v*>(&As[wm + mb * 16 + lr][ks + lg * 8]);
            #pragma unroll
            for (int nb = 0; nb < 4; nb++)
                bfr[nb] = *reinterpret_cast<const s8v*>(&Bs[wn + nb * 16 + lr][ks + lg * 8]);
            #pragma unroll
            for (int mb = 0; mb < 4; mb++)
                #pragma unroll
                for (int nb = 0; nb < 4; nb++)
                    acc[mb][nb] = __builtin_amdgcn_mfma_f32_16x16x32_bf16(af[mb], bfr[nb], acc[mb][nb], 0, 0, 0);
        }
    }

    #pragma unroll
    for (int mb = 0; mb < 4; mb++) {
        #pragma unroll
        for (int nb = 0; nb < 4; nb++) {
            int col = n0 + wn + nb * 16 + lr;
            float bv = bias[col];
            #pragma unroll
            for (int r = 0; r < 4; r++) {
                int row = m0 + wm + mb * 16 + lg * 4 + r;
                float val = acc[mb][nb][r] + bv;
                if (OUT_BF16)
                    reinterpret_cast<ushort*>(Cout)[(size_t)row * N + col] = f2bf(val);
                else
                    reinterpret_cast<float*>(Cout)[(size_t)row * N + col] = val;
            }
        }
    }
}

// ---------------- swapped-operand attention tile ----------------
// S^T = K·Q^T via mfma(K,Q): lane owns q = qtb+(wave&1)*16+lr, s = sb+cb*16+lg*4+r.
// Softmax fully per-lane (15 fmax in-lane + 2 shfl). O^T accumulated via mfma(V^T, P^T).
__device__ __forceinline__ void attn_tile_sw(
    const s8v qf0, const s8v qf1, int q_abs, int qb, int sb,
    int lr, int lg,
    const ushort (*Ks)[72], const ushort (*Vs)[72],
    ushort (*pT)[72],                    // per-wave [16 q][72] scratch
    const float* rel_lds,                // rel_emb * log2e
    float& m, float& l, f4v* oT)
{
    const float SC = 0.125f * 1.44269504f;   // qk-scale * log2e
    f4v sacc[4];
    __builtin_amdgcn_s_setprio(1);
    #pragma unroll
    for (int cb = 0; cb < 4; cb++) {
        sacc[cb] = (f4v){0.f, 0.f, 0.f, 0.f};
        s8v kf0 = *(const s8v*)&Ks[cb * 16 + lr][lg * 8];
        s8v kf1 = *(const s8v*)&Ks[cb * 16 + lr][32 + lg * 8];
        sacc[cb] = __builtin_amdgcn_mfma_f32_16x16x32_bf16(kf0, qf0, sacc[cb], 0, 0, 0);
        sacc[cb] = __builtin_amdgcn_mfma_f32_16x16x32_bf16(kf1, qf1, sacc[cb], 0, 0, 0);
    }
    __builtin_amdgcn_s_setprio(0);

    if (sb + 192 <= qb) {
        // far tile: all rel distances clip to -128 -> uniform bias, no causal mask
        float c = rel_lds[0];
        #pragma unroll
        for (int cb = 0; cb < 4; cb++)
            #pragma unroll
            for (int r = 0; r < 4; r++)
                sacc[cb][r] = sacc[cb][r] * SC + c;
    } else {
        #pragma unroll
        for (int cb = 0; cb < 4; cb++) {
            #pragma unroll
            for (int r = 0; r < 4; r++) {
                int s = sb + cb * 16 + lg * 4 + r;
                int rel = s - q_abs;
                rel = (rel < -128 ? -128 : (rel > 128 ? 128 : rel)) + 128;
                float val = sacc[cb][r] * SC + rel_lds[rel];
                if (s > q_abs) val = -3.0e38f;
                sacc[cb][r] = val;
            }
        }
    }

    // row max: in-lane tree over 16 + 2 shfl across the 4 lg-lanes
    float pm0 = fmaxf(fmaxf(sacc[0][0], sacc[0][1]), fmaxf(sacc[0][2], sacc[0][3]));
    float pm1 = fmaxf(fmaxf(sacc[1][0], sacc[1][1]), fmaxf(sacc[1][2], sacc[1][3]));
    float pm2 = fmaxf(fmaxf(sacc[2][0], sacc[2][1]), fmaxf(sacc[2][2], sacc[2][3]));
    float pm3 = fmaxf(fmaxf(sacc[3][0], sacc[3][1]), fmaxf(sacc[3][2], sacc[3][3]));
    float pm = fmaxf(fmaxf(pm0, pm1), fmaxf(pm2, pm3));
    pm = fmaxf(pm, __shfl_xor(pm, 16, 64));
    pm = fmaxf(pm, __shfl_xor(pm, 32, 64));

    // defer-max (T13): only rescale when the running max grew by > 8 (log2 units)
    if (__any(pm > m + 8.0f)) {
        float mnew = fmaxf(m, pm);
        float alpha = exp2f(m - mnew);
        l *= alpha;
        #pragma unroll
        for (int d = 0; d < 4; d++)
            #pragma unroll
            for (int r = 0; r < 4; r++)
                oT[d][r] *= alpha;
        m = mnew;
    }

    // p = exp2(s - m); in-lane sum + 2 shfl
    float sum = 0.f;
    #pragma unroll
    for (int cb = 0; cb < 4; cb++) {
        #pragma unroll
        for (int r = 0; r < 4; r++) {
            float p = exp2f(sacc[cb][r] - m);
            sacc[cb][r] = p;
            sum += p;
        }
    }
    sum += __shfl_xor(sum, 16, 64);
    sum += __shfl_xor(sum, 32, 64);
    l += sum;

    // pack P^T -> per-wave LDS: pT[q=lr][s], 4 x ds_write_b64
    #pragma unroll
    for (int cb = 0; cb < 4; cb++) {
        unsigned lo = (unsigned)f2bf(sacc[cb][0]) | ((unsigned)f2bf(sacc[cb][1]) << 16);
        unsigned hi = (unsigned)f2bf(sacc[cb][2]) | ((unsigned)f2bf(sacc[cb][3]) << 16);
        *(unsigned long long*)&pT[lr][cb * 16 + lg * 4] =
            (unsigned long long)lo | ((unsigned long long)hi << 32);
    }

    // O^T += V^T · P^T  (A = V^T frag row=d, B = P^T frag col=q)
    __builtin_amdgcn_s_setprio(1);
    #pragma unroll
    for (int ch = 0; ch < 2; ch++) {
        s8v pf = *(const s8v*)&pT[lr][ch * 32 + lg * 8];
        #pragma unroll
        for (int d = 0; d < 4; d++) {
            s8v vf = *(const s8v*)&Vs[d * 16 + lr][ch * 32 + lg * 8];
            oT[d] = __builtin_amdgcn_mfma_f32_16x16x32_bf16(vf, pf, oT[d], 0, 0, 0);
        }
    }
    __builtin_amdgcn_s_setprio(0);
}

// normalize O^T, transpose through per-wave LDS, coalesced store
__device__ __forceinline__ void store_O(
    f4v* oT, float l, int lr, int lg, int lane, int qrow0,
    ushort (*pT)[72], size_t rowb, int h, ushort* __restrict__ attn_out)
{
    float inv = 1.0f / l;
    #pragma unroll
    for (int d = 0; d < 4; d++) {
        unsigned lo = (unsigned)f2bf(oT[d][0] * inv) | ((unsigned)f2bf(oT[d][1] * inv) << 16);
        unsigned hi = (unsigned)f2bf(oT[d][2] * inv) | ((unsigned)f2bf(oT[d][3] * inv) << 16);
        *(unsigned long long*)&pT[lr][d * 16 + lg * 4] =
            (unsigned long long)lo | ((unsigned long long)hi << 32);
    }
    int q_r = lane >> 2, part = lane & 3;
    s8v a = *(const s8v*)&pT[q_r][part * 16];
    s8v b = *(const s8v*)&pT[q_r][part * 16 + 8];
    ushort* dst = attn_out + (rowb + qrow0 + q_r) * 1024 + h * 64 + part * 16;
    *(s8v*)dst = a;
    *(s8v*)(dst + 8) = b;
}

// ---------------- flash attention: QBLK=32, mirrored pairs, 4 blocks/CU ----------------
// Grid (32, B*16). Pair p=(x+y)&31 owns q-tiles lo=p, hi=63-p (32 rows each).
// Waves 0,1 -> hi tile rows 0-15/16-31; waves 2,3 -> lo tile. Shared K/V staging.
__global__ __launch_bounds__(256, 4) void attn_kernel(
    const ushort* __restrict__ qkv, const ushort* __restrict__ vt_g,
    const float* __restrict__ rel_emb, ushort* __restrict__ attn_out, int T)
{
    __shared__ ushort Ks[64][72];
    __shared__ ushort Vs[64][72];
    __shared__ ushort p_lds[4][16][72];
    __shared__ float rel_lds[257];

    const int t = threadIdx.x;
    const int bh = blockIdx.y;
    const int p = (blockIdx.x + bh) & 31;       // diagonal remap: mix spans per CU
    const int lo = p, hi = 63 - p;              // q-tiles of 32 rows
    const int b = bh >> 4, h = bh & 15;
    const size_t rowb = (size_t)b * T;

    for (int i = t; i < 257; i += 256) rel_lds[i] = rel_emb[i * 16 + h] * 1.44269504f;

    const int wave = t >> 6, lane = t & 63;
    const int lr = lane & 15, lg = lane >> 4;
    const int sr = t >> 3, sc = (t & 7) * 8;

    const int my_tile = (wave < 2) ? hi : lo;
    const int qtb = my_tile * 32;               // tile base row
    const int qrow0 = qtb + (wave & 1) * 16;    // this wave's 16-row slice
    const int qa = qrow0 + lr;                  // absolute q row for this lane
    const int my_nt = (qtb + 31) / 64 + 1;      // s-tiles this wave needs
    const int ntH = ((63 - p) * 32 + 31) / 64 + 1;  // block loop count (hi's nt)

    const ushort* kbase = qkv + rowb * 3072 + 1024 + h * 64;
    const ushort* vbase = vt_g + (size_t)bh * 64 * T;

    const ushort* qptr = qkv + (rowb + qa) * 3072 + h * 64;
    s8v qf0 = *(const s8v*)(qptr + lg * 8);
    s8v qf1 = *(const s8v*)(qptr + 32 + lg * 8);

    float m = -3.0e38f, l = 0.f;
    f4v oT[4];
    #pragma unroll
    for (int d = 0; d < 4; d++) oT[d] = (f4v){0.f, 0.f, 0.f, 0.f};

    s8v ka0 = *(const s8v*)(kbase + (size_t)sr * 3072 + sc);
    s8v ka1 = *(const s8v*)(kbase + (size_t)(32 + sr) * 3072 + sc);
    s8v va0 = *(const s8v*)(vbase + (size_t)sr * T + sc);
    s8v va1 = *(const s8v*)(vbase + (size_t)(32 + sr) * T + sc);

    for (int st = 0; st < ntH; ++st) {
        const int sb = st * 64;
        __syncthreads();
        *(s8v*)&Ks[sr][sc]      = ka0;
        *(s8v*)&Ks[32 + sr][sc] = ka1;
        *(s8v*)&Vs[sr][sc]      = va0;
        *(s8v*)&Vs[32 + sr][sc] = va1;
        __syncthreads();

        if (st + 1 < ntH) {
            const int sn = sb + 64;
            ka0 = *(const s8v*)(kbase + (size_t)(sn + sr) * 3072 + sc);
            ka1 = *(const s8v*)(kbase + (size_t)(sn + 32 + sr) * 3072 + sc);
            va0 = *(const s8v*)(vbase + (size_t)sr * T + sn + sc);
            va1 = *(const s8v*)(vbase + (size_t)(32 + sr) * T + sn + sc);
        }

        if (st < my_nt)     // wave-uniform branch
            attn_tile_sw(qf0, qf1, qa, qtb, sb, lr, lg, Ks, Vs, p_lds[wave], rel_lds, m, l, oT);
    }

    store_O(oT, l, lr, lg, lane, qrow0, p_lds[wave], rowb, h, attn_out);
}

extern "C" void kernel_launch(void* const* d_in, const int* in_sizes, int n_in,
                              void* d_out, int out_size, void* d_ws, size_t ws_size,
                              hipStream_t stream) {
    const float* x       = (const float*)d_in[0];   // [B,T,1024]
    const float* Wqkv    = (const float*)d_in[1];   // [1024,3072]
    const float* bqkv    = (const float*)d_in[2];   // [3072]
    const float* Wout    = (const float*)d_in[3];   // [1024,1024]
    const float* bout    = (const float*)d_in[4];   // [1024]
    const float* rel_emb = (const float*)d_in[5];   // [257,16]
    float* out = (float*)d_out;

    const int M = in_sizes[0] / 1024;   // B*T = 4096
    const int T = 2048;
    const int B = M / T;

    ushort* x_bf = (ushort*)d_ws;                        // M*1024 bf16
    ushort* Wq_t = x_bf + (size_t)M * 1024;              // 3072*1024
    ushort* Wo_t = Wq_t + (size_t)3072 * 1024;           // 1024*1024
    ushort* qkv  = Wo_t + (size_t)1024 * 1024;           // M*3072
    ushort* attn = qkv + (size_t)M * 3072;               // M*1024
    ushort* vt_g = attn + (size_t)M * 1024;              // B*16*64*T = M*1024

    hipLaunchKernelGGL(cast_bf16_kernel, dim3((M * 1024 / 4 + 255) / 256), dim3(256), 0, stream,
                       x, x_bf, M * 1024 / 4);
    hipLaunchKernelGGL(transpose_cast_kernel, dim3(3072 / 32, 1024 / 32), dim3(256), 0, stream,
                       Wqkv, Wq_t, 1024, 3072);
    hipLaunchKernelGGL(transpose_cast_kernel, dim3(1024 / 32, 1024 / 32), dim3(256), 0, stream,
                       Wout, Wo_t, 1024, 1024);
    hipLaunchKernelGGL((gemm_bt_kernel<true>), dim3(3072 / 128, M / 128), dim3(256), 0, stream,
                       x_bf, Wq_t, bqkv, (void*)qkv, M, 3072, 1024);
    hipLaunchKernelGGL(vtrans_kernel, dim3(T / 64, B * 16), dim3(256), 0, stream,
                       qkv, vt_g, T);
    hipLaunchKernelGGL(attn_kernel, dim3(32, B * 16), dim3(256), 0, stream,
                       qkv, vt_g, rel_emb, attn, T);
    hipLaunchKernelGGL((gemm_bt_kernel<false>), dim3(1024 / 128, M / 128), dim3(256), 0, stream,
                       attn, Wo_t, bout, (void*)out, M, 1024, 1024);
}

// Round 8
// 224.939 us; speedup vs baseline: 1.0420x; 1.0420x over previous
//
#include <hip/hip_runtime.h>
#include <hip/hip_bf16.h>

typedef __attribute__((ext_vector_type(8))) short s8v;   // 8 x bf16 raw (4 VGPRs)
typedef __attribute__((ext_vector_type(4))) float f4v;   // MFMA accumulator

// native RNE float->bf16 (compiles to v_cvt_pk_bf16_f32 pairs; m240: don't hand-write)
__device__ __forceinline__ ushort f2bf(float f) {
    union { __hip_bfloat16 h; ushort u; } cv;
    cv.h = __float2bfloat16(f);
    return cv.u;
}
__device__ __forceinline__ unsigned packbf2(float a, float b) {
    union { __hip_bfloat162 h; unsigned u; } cv;
    cv.h = __float22bfloat162_rn(float2{a, b});
    return cv.u;
}

// async global->LDS, 16B per lane; LDS dest is wave-uniform base + lane*16
typedef __attribute__((address_space(1))) void gvoid;
typedef __attribute__((address_space(3))) void lvoid;
__device__ __forceinline__ void gl_lds16(const ushort* g, ushort* l) {
    __builtin_amdgcn_global_load_lds((gvoid*)g, (lvoid*)l, 16, 0, 0);
}

// ---------------- cast fp32 -> bf16 (vectorized) ----------------
__global__ void cast_bf16_kernel(const float* __restrict__ in, ushort* __restrict__ out, int n4) {
    int i = blockIdx.x * blockDim.x + threadIdx.x;
    if (i >= n4) return;
    float4 v = reinterpret_cast<const float4*>(in)[i];
    uint2 o;
    o.x = packbf2(v.x, v.y);
    o.y = packbf2(v.z, v.w);
    reinterpret_cast<uint2*>(out)[i] = o;
}

// ---------------- transpose + cast: in[R][C] fp32 -> out[C][R] bf16 ----------------
__global__ void transpose_cast_kernel(const float* __restrict__ in, ushort* __restrict__ out,
                                      int R, int C) {
    __shared__ float tile[32][33];
    int c0 = blockIdx.x * 32, r0 = blockIdx.y * 32;
    int tx = threadIdx.x & 31, ty = threadIdx.x >> 5;
    #pragma unroll
    for (int i = 0; i < 32; i += 8)
        tile[ty + i][tx] = in[(size_t)(r0 + ty + i) * C + c0 + tx];
    __syncthreads();
    #pragma unroll
    for (int i = 0; i < 32; i += 8)
        out[(size_t)(c0 + ty + i) * R + r0 + tx] = f2bf(tile[tx][ty + i]);
}

// ---------------- V transpose: qkv V part -> Vt[b*16+h][64 d][T s] bf16 ----------------
__global__ __launch_bounds__(256) void vtrans_kernel(
    const ushort* __restrict__ qkv, ushort* __restrict__ vt_g, int T)
{
    __shared__ ushort tile[64][72];
    const int sb = blockIdx.x * 64, bh = blockIdx.y;
    const int b = bh >> 4, h = bh & 15;
    const int t = threadIdx.x;
    const int r0 = t >> 3, c0 = (t & 7) * 8;
    const ushort* vsrc = qkv + (size_t)b * T * 3072 + 2048 + h * 64;
    *(s8v*)&tile[r0][c0]      = *(const s8v*)(vsrc + (size_t)(sb + r0) * 3072 + c0);
    *(s8v*)&tile[32 + r0][c0] = *(const s8v*)(vsrc + (size_t)(sb + 32 + r0) * 3072 + c0);
    __syncthreads();
    ushort* vdst = vt_g + (size_t)bh * 64 * T;
    s8v o0, o1;
    #pragma unroll
    for (int j = 0; j < 8; j++) {
        o0[j] = (short)tile[c0 + j][r0];
        o1[j] = (short)tile[c0 + j][32 + r0];
    }
    *(s8v*)(vdst + (size_t)r0 * T + sb + c0)        = o0;
    *(s8v*)(vdst + (size_t)(32 + r0) * T + sb + c0) = o1;
}

// ---------------- bf16 MFMA GEMM (m97 structure): C = A * Bt^T + bias ----------------
template <bool OUT_BF16>
__global__ __launch_bounds__(256) void gemm_bt_kernel(
    const ushort* __restrict__ A, const ushort* __restrict__ Bt,
    const float* __restrict__ bias, void* __restrict__ Cout,
    int M, int N, int K)
{
    __shared__ ushort As[128][64];   // linear (global_load_lds requires contiguous dest)
    __shared__ ushort Bs[128][64];
    const int t = threadIdx.x;
    const int m0 = blockIdx.y * 128, n0 = blockIdx.x * 128;
    const int wave = t >> 6, lane = t & 63;
    const int lr = lane & 15, lg = lane >> 4;
    const int wm = (wave >> 1) * 64, wn = (wave & 1) * 64;
    const int lrow = lane >> 3;
    const int lcol = (lane & 7) * 8;

    f4v acc[4][4];
    #pragma unroll
    for (int i = 0; i < 4; i++)
        #pragma unroll
        for (int j = 0; j < 4; j++)
            acc[i][j] = (f4v){0.f, 0.f, 0.f, 0.f};

    for (int k0 = 0; k0 < K; k0 += 64) {
        __syncthreads();
        #pragma unroll
        for (int i = 0; i < 4; i++) {
            int j = wave * 4 + i;
            int row = j * 8 + lrow;
            gl_lds16(A  + (size_t)(m0 + row) * K + k0 + lcol, &As[j * 8][0]);
            gl_lds16(Bt + (size_t)(n0 + row) * K + k0 + lcol, &Bs[j * 8][0]);
        }
        __syncthreads();
        #pragma unroll
        for (int ks = 0; ks < 64; ks += 32) {
            s8v af[4], bfr[4];
            #pragma unroll
            for (int mb = 0; mb < 4; mb++)
                af[mb] = *reinterpret_cast<const s8v*>(&As[wm + mb * 16 + lr][ks + lg * 8]);
            #pragma unroll
            for (int nb = 0; nb < 4; nb++)
                bfr[nb] = *reinterpret_cast<const s8v*>(&Bs[wn + nb * 16 + lr][ks + lg * 8]);
            #pragma unroll
            for (int mb = 0; mb < 4; mb++)
                #pragma unroll
                for (int nb = 0; nb < 4; nb++)
                    acc[mb][nb] = __builtin_amdgcn_mfma_f32_16x16x32_bf16(af[mb], bfr[nb], acc[mb][nb], 0, 0, 0);
        }
    }

    #pragma unroll
    for (int mb = 0; mb < 4; mb++) {
        #pragma unroll
        for (int nb = 0; nb < 4; nb++) {
            int col = n0 + wn + nb * 16 + lr;
            float bv = bias[col];
            #pragma unroll
            for (int r = 0; r < 4; r++) {
                int row = m0 + wm + mb * 16 + lg * 4 + r;
                float val = acc[mb][nb][r] + bv;
                if (OUT_BF16)
                    reinterpret_cast<ushort*>(Cout)[(size_t)row * N + col] = f2bf(val);
                else
                    reinterpret_cast<float*>(Cout)[(size_t)row * N + col] = val;
            }
        }
    }
}

// ---------------- swapped-operand attention tile ----------------
// S^T = K·Q^T via mfma(K,Q): lane owns q = qb+wave*16+lr, s = sb+cb*16+lg*4+r.
// Softmax fully per-lane (15 fmax in-lane + 2 shfl). O^T accumulated via mfma(V^T, P^T).
__device__ __forceinline__ void attn_tile_sw(
    const s8v qf0, const s8v qf1, int q_abs, int qb, int sb,
    int lr, int lg,
    const ushort (*Ks)[72], const ushort (*Vs)[72],
    ushort (*pT)[72],                    // per-wave [16 q][72] scratch
    const float* rel_lds,                // rel_emb * log2e
    float& m, float& l, f4v* oT)
{
    const float SC = 0.125f * 1.44269504f;   // qk-scale * log2e
    f4v sacc[4];
    __builtin_amdgcn_s_setprio(1);
    #pragma unroll
    for (int cb = 0; cb < 4; cb++) {
        sacc[cb] = (f4v){0.f, 0.f, 0.f, 0.f};
        s8v kf0 = *(const s8v*)&Ks[cb * 16 + lr][lg * 8];
        s8v kf1 = *(const s8v*)&Ks[cb * 16 + lr][32 + lg * 8];
        sacc[cb] = __builtin_amdgcn_mfma_f32_16x16x32_bf16(kf0, qf0, sacc[cb], 0, 0, 0);
        sacc[cb] = __builtin_amdgcn_mfma_f32_16x16x32_bf16(kf1, qf1, sacc[cb], 0, 0, 0);
    }
    __builtin_amdgcn_s_setprio(0);

    if (sb + 192 <= qb) {
        // far tile: all rel distances clip to -128 -> uniform bias, no causal mask
        float c = rel_lds[0];
        #pragma unroll
        for (int cb = 0; cb < 4; cb++)
            #pragma unroll
            for (int r = 0; r < 4; r++)
                sacc[cb][r] = sacc[cb][r] * SC + c;
    } else {
        #pragma unroll
        for (int cb = 0; cb < 4; cb++) {
            #pragma unroll
            for (int r = 0; r < 4; r++) {
                int s = sb + cb * 16 + lg * 4 + r;
                int rel = s - q_abs;
                rel = (rel < -128 ? -128 : (rel > 128 ? 128 : rel)) + 128;
                float val = sacc[cb][r] * SC + rel_lds[rel];
                if (s > q_abs) val = -3.0e38f;
                sacc[cb][r] = val;
            }
        }
    }

    // row max: in-lane tree over 16 + 2 shfl across the 4 lg-lanes
    float pm0 = fmaxf(fmaxf(sacc[0][0], sacc[0][1]), fmaxf(sacc[0][2], sacc[0][3]));
    float pm1 = fmaxf(fmaxf(sacc[1][0], sacc[1][1]), fmaxf(sacc[1][2], sacc[1][3]));
    float pm2 = fmaxf(fmaxf(sacc[2][0], sacc[2][1]), fmaxf(sacc[2][2], sacc[2][3]));
    float pm3 = fmaxf(fmaxf(sacc[3][0], sacc[3][1]), fmaxf(sacc[3][2], sacc[3][3]));
    float pm = fmaxf(fmaxf(pm0, pm1), fmaxf(pm2, pm3));
    pm = fmaxf(pm, __shfl_xor(pm, 16, 64));
    pm = fmaxf(pm, __shfl_xor(pm, 32, 64));

    // defer-max (T13): only rescale when the running max grew by > 8 (log2 units)
    if (__any(pm > m + 8.0f)) {
        float mnew = fmaxf(m, pm);
        float alpha = exp2f(m - mnew);
        l *= alpha;
        #pragma unroll
        for (int d = 0; d < 4; d++)
            #pragma unroll
            for (int r = 0; r < 4; r++)
                oT[d][r] *= alpha;
        m = mnew;
    }

    // p = exp2(s - m); in-lane sum + 2 shfl
    float sum = 0.f;
    #pragma unroll
    for (int cb = 0; cb < 4; cb++) {
        #pragma unroll
        for (int r = 0; r < 4; r++) {
            float p = exp2f(sacc[cb][r] - m);
            sacc[cb][r] = p;
            sum += p;
        }
    }
    sum += __shfl_xor(sum, 16, 64);
    sum += __shfl_xor(sum, 32, 64);
    l += sum;

    // pack P^T -> per-wave LDS: pT[q=lr][s], 4 x ds_write_b64 (v_cvt_pk_bf16_f32 packs)
    #pragma unroll
    for (int cb = 0; cb < 4; cb++) {
        unsigned lo = packbf2(sacc[cb][0], sacc[cb][1]);
        unsigned hi = packbf2(sacc[cb][2], sacc[cb][3]);
        *(unsigned long long*)&pT[lr][cb * 16 + lg * 4] =
            (unsigned long long)lo | ((unsigned long long)hi << 32);
    }

    // O^T += V^T · P^T  (A = V^T frag row=d, B = P^T frag col=q)
    __builtin_amdgcn_s_setprio(1);
    #pragma unroll
    for (int ch = 0; ch < 2; ch++) {
        s8v pf = *(const s8v*)&pT[lr][ch * 32 + lg * 8];
        #pragma unroll
        for (int d = 0; d < 4; d++) {
            s8v vf = *(const s8v*)&Vs[d * 16 + lr][ch * 32 + lg * 8];
            oT[d] = __builtin_amdgcn_mfma_f32_16x16x32_bf16(vf, pf, oT[d], 0, 0, 0);
        }
    }
    __builtin_amdgcn_s_setprio(0);
}

// normalize O^T, transpose through per-wave LDS, coalesced store
__device__ __forceinline__ void store_O(
    f4v* oT, float l, int lr, int lg, int lane, int wave,
    ushort (*pT)[72], int qb, size_t rowb, int h, ushort* __restrict__ attn_out)
{
    float inv = 1.0f / l;
    #pragma unroll
    for (int d = 0; d < 4; d++) {
        unsigned lo = packbf2(oT[d][0] * inv, oT[d][1] * inv);
        unsigned hi = packbf2(oT[d][2] * inv, oT[d][3] * inv);
        *(unsigned long long*)&pT[lr][d * 16 + lg * 4] =
            (unsigned long long)lo | ((unsigned long long)hi << 32);
    }
    int q_r = lane >> 2, part = lane & 3;
    s8v a = *(const s8v*)&pT[q_r][part * 16];
    s8v b = *(const s8v*)&pT[q_r][part * 16 + 8];
    ushort* dst = attn_out + (rowb + qb + wave * 16 + q_r) * 1024 + h * 64 + part * 16;
    *(s8v*)dst = a;
    *(s8v*)(dst + 8) = b;
}

// ---------------- flash attention, paired q-tiles, swapped softmax ----------------
__global__ __launch_bounds__(256, 2) void attn_kernel(
    const ushort* __restrict__ qkv, const ushort* __restrict__ vt_g,
    const float* __restrict__ rel_emb, ushort* __restrict__ attn_out, int T)
{
    __shared__ ushort Ks[64][72];
    __shared__ ushort Vs[64][72];
    __shared__ ushort p_lds[4][16][72];
    __shared__ float rel_lds[257];

    const int t = threadIdx.x;
    const int nQ = T / 64;
    const int lo = blockIdx.x;
    const int hi = nQ - 1 - lo;
    const int qbL = lo * 64, qbH = hi * 64;
    const int bh = blockIdx.y;
    const int b = bh >> 4, h = bh & 15;
    const size_t rowb = (size_t)b * T;

    for (int i = t; i < 257; i += 256) rel_lds[i] = rel_emb[i * 16 + h] * 1.44269504f;

    const int wave = t >> 6, lane = t & 63;
    const int lr = lane & 15, lg = lane >> 4;
    const int sr = t >> 3, sc = (t & 7) * 8;

    const ushort* kbase = qkv + rowb * 3072 + 1024 + h * 64;
    const ushort* vbase = vt_g + (size_t)bh * 64 * T;

    const int qaL = qbL + wave * 16 + lr;
    const int qaH = qbH + wave * 16 + lr;
    const ushort* qptrL = qkv + (rowb + qaL) * 3072 + h * 64;
    s8v qL0 = *(const s8v*)(qptrL + lg * 8);
    s8v qL1 = *(const s8v*)(qptrL + 32 + lg * 8);
    const ushort* qptrH = qkv + (rowb + qaH) * 3072 + h * 64;
    s8v qH0 = *(const s8v*)(qptrH + lg * 8);
    s8v qH1 = *(const s8v*)(qptrH + 32 + lg * 8);

    float mL = -3.0e38f, lL = 0.f, mH = -3.0e38f, lH = 0.f;
    f4v oL[4], oH[4];
    #pragma unroll
    for (int d = 0; d < 4; d++) { oL[d] = (f4v){0.f,0.f,0.f,0.f}; oH[d] = (f4v){0.f,0.f,0.f,0.f}; }

    const int nt = hi + 1;

    s8v ka0 = *(const s8v*)(kbase + (size_t)sr * 3072 + sc);
    s8v ka1 = *(const s8v*)(kbase + (size_t)(32 + sr) * 3072 + sc);
    s8v va0 = *(const s8v*)(vbase + (size_t)sr * T + sc);
    s8v va1 = *(const s8v*)(vbase + (size_t)(32 + sr) * T + sc);

    for (int st = 0; st < nt; ++st) {
        const int sb = st * 64;
        __syncthreads();
        *(s8v*)&Ks[sr][sc]      = ka0;
        *(s8v*)&Ks[32 + sr][sc] = ka1;
        *(s8v*)&Vs[sr][sc]      = va0;
        *(s8v*)&Vs[32 + sr][sc] = va1;
        __syncthreads();

        if (st + 1 < nt) {
            const int sn = sb + 64;
            ka0 = *(const s8v*)(kbase + (size_t)(sn + sr) * 3072 + sc);
            ka1 = *(const s8v*)(kbase + (size_t)(sn + 32 + sr) * 3072 + sc);
            va0 = *(const s8v*)(vbase + (size_t)sr * T + sn + sc);
            va1 = *(const s8v*)(vbase + (size_t)(32 + sr) * T + sn + sc);
        }

        attn_tile_sw(qH0, qH1, qaH, qbH, sb, lr, lg, Ks, Vs, p_lds[wave], rel_lds, mH, lH, oH);
        if (st <= lo)
            attn_tile_sw(qL0, qL1, qaL, qbL, sb, lr, lg, Ks, Vs, p_lds[wave], rel_lds, mL, lL, oL);
    }

    store_O(oH, lH, lr, lg, lane, wave, p_lds[wave], qbH, rowb, h, attn_out);
    store_O(oL, lL, lr, lg, lane, wave, p_lds[wave], qbL, rowb, h, attn_out);
}

extern "C" void kernel_launch(void* const* d_in, const int* in_sizes, int n_in,
                              void* d_out, int out_size, void* d_ws, size_t ws_size,
                              hipStream_t stream) {
    const float* x       = (const float*)d_in[0];   // [B,T,1024]
    const float* Wqkv    = (const float*)d_in[1];   // [1024,3072]
    const float* bqkv    = (const float*)d_in[2];   // [3072]
    const float* Wout    = (const float*)d_in[3];   // [1024,1024]
    const float* bout    = (const float*)d_in[4];   // [1024]
    const float* rel_emb = (const float*)d_in[5];   // [257,16]
    float* out = (float*)d_out;

    const int M = in_sizes[0] / 1024;   // B*T = 4096
    const int T = 2048;
    const int B = M / T;

    ushort* x_bf = (ushort*)d_ws;                        // M*1024 bf16
    ushort* Wq_t = x_bf + (size_t)M * 1024;              // 3072*1024
    ushort* Wo_t = Wq_t + (size_t)3072 * 1024;           // 1024*1024
    ushort* qkv  = Wo_t + (size_t)1024 * 1024;           // M*3072
    ushort* attn = qkv + (size_t)M * 3072;               // M*1024
    ushort* vt_g = attn + (size_t)M * 1024;              // B*16*64*T = M*1024

    hipLaunchKernelGGL(cast_bf16_kernel, dim3((M * 1024 / 4 + 255) / 256), dim3(256), 0, stream,
                       x, x_bf, M * 1024 / 4);
    hipLaunchKernelGGL(transpose_cast_kernel, dim3(3072 / 32, 1024 / 32), dim3(256), 0, stream,
                       Wqkv, Wq_t, 1024, 3072);
    hipLaunchKernelGGL(transpose_cast_kernel, dim3(1024 / 32, 1024 / 32), dim3(256), 0, stream,
                       Wout, Wo_t, 1024, 1024);
    hipLaunchKernelGGL((gemm_bt_kernel<true>), dim3(3072 / 128, M / 128), dim3(256), 0, stream,
                       x_bf, Wq_t, bqkv, (void*)qkv, M, 3072, 1024);
    hipLaunchKernelGGL(vtrans_kernel, dim3(T / 64, B * 16), dim3(256), 0, stream,
                       qkv, vt_g, T);
    hipLaunchKernelGGL(attn_kernel, dim3((T / 64) / 2, B * 16), dim3(256), 0, stream,
                       qkv, vt_g, rel_emb, attn, T);
    hipLaunchKernelGGL((gemm_bt_kernel<false>), dim3(1024 / 128, M / 128), dim3(256), 0, stream,
                       attn, Wo_t, bout, (void*)out, M, 1024, 1024);
}

// Round 10
// 220.536 us; speedup vs baseline: 1.0628x; 1.0200x over previous
//
#include <hip/hip_runtime.h>
#include <hip/hip_bf16.h>

typedef __attribute__((ext_vector_type(8))) short s8v;   // 8 x bf16 raw (4 VGPRs)
typedef __attribute__((ext_vector_type(4))) float f4v;   // MFMA accumulator

__device__ __forceinline__ ushort f2bf(float f) {
    union { float f; unsigned u; } cv; cv.f = f;
    unsigned u = cv.u;
    unsigned lsb = (u >> 16) & 1u;
    u += 0x7fffu + lsb;          // RNE round to bf16 (manual — faster than intrinsic, R8 A/B)
    return (ushort)(u >> 16);
}

// async global->LDS, 16B per lane; LDS dest is wave-uniform base + lane*16
typedef __attribute__((address_space(1))) void gvoid;
typedef __attribute__((address_space(3))) void lvoid;
__device__ __forceinline__ void gl_lds16(const ushort* g, ushort* l) {
    __builtin_amdgcn_global_load_lds((gvoid*)g, (lvoid*)l, 16, 0, 0);
}

// ---------------- cast fp32 -> bf16 (vectorized) ----------------
__global__ void cast_bf16_kernel(const float* __restrict__ in, ushort* __restrict__ out, int n4) {
    int i = blockIdx.x * blockDim.x + threadIdx.x;
    if (i >= n4) return;
    float4 v = reinterpret_cast<const float4*>(in)[i];
    ushort4 o;
    o.x = f2bf(v.x); o.y = f2bf(v.y); o.z = f2bf(v.z); o.w = f2bf(v.w);
    reinterpret_cast<ushort4*>(out)[i] = o;
}

// ---------------- transpose + cast: in[R][C] fp32 -> out[C][R] bf16 ----------------
__global__ void transpose_cast_kernel(const float* __restrict__ in, ushort* __restrict__ out,
                                      int R, int C) {
    __shared__ float tile[32][33];
    int c0 = blockIdx.x * 32, r0 = blockIdx.y * 32;
    int tx = threadIdx.x & 31, ty = threadIdx.x >> 5;
    #pragma unroll
    for (int i = 0; i < 32; i += 8)
        tile[ty + i][tx] = in[(size_t)(r0 + ty + i) * C + c0 + tx];
    __syncthreads();
    #pragma unroll
    for (int i = 0; i < 32; i += 8)
        out[(size_t)(c0 + ty + i) * R + r0 + tx] = f2bf(tile[tx][ty + i]);
}

// ---------------- V transpose: qkv V part -> Vt[b*16+h][64 d][T s] bf16 ----------------
__global__ __launch_bounds__(256) void vtrans_kernel(
    const ushort* __restrict__ qkv, ushort* __restrict__ vt_g, int T)
{
    __shared__ ushort tile[64][72];
    const int sb = blockIdx.x * 64, bh = blockIdx.y;
    const int b = bh >> 4, h = bh & 15;
    const int t = threadIdx.x;
    const int r0 = t >> 3, c0 = (t & 7) * 8;
    const ushort* vsrc = qkv + (size_t)b * T * 3072 + 2048 + h * 64;
    *(s8v*)&tile[r0][c0]      = *(const s8v*)(vsrc + (size_t)(sb + r0) * 3072 + c0);
    *(s8v*)&tile[32 + r0][c0] = *(const s8v*)(vsrc + (size_t)(sb + 32 + r0) * 3072 + c0);
    __syncthreads();
    ushort* vdst = vt_g + (size_t)bh * 64 * T;
    s8v o0, o1;
    #pragma unroll
    for (int j = 0; j < 8; j++) {
        o0[j] = (short)tile[c0 + j][r0];
        o1[j] = (short)tile[c0 + j][32 + r0];
    }
    *(s8v*)(vdst + (size_t)r0 * T + sb + c0)        = o0;
    *(s8v*)(vdst + (size_t)(32 + r0) * T + sb + c0) = o1;
}

// ---------------- bf16 MFMA GEMM (m97 structure): C = A * Bt^T + bias ----------------
template <bool OUT_BF16>
__global__ __launch_bounds__(256) void gemm_bt_kernel(
    const ushort* __restrict__ A, const ushort* __restrict__ Bt,
    const float* __restrict__ bias, void* __restrict__ Cout,
    int M, int N, int K)
{
    __shared__ ushort As[128][64];   // linear (global_load_lds requires contiguous dest)
    __shared__ ushort Bs[128][64];
    const int t = threadIdx.x;
    const int m0 = blockIdx.y * 128, n0 = blockIdx.x * 128;
    const int wave = t >> 6, lane = t & 63;
    const int lr = lane & 15, lg = lane >> 4;
    const int wm = (wave >> 1) * 64, wn = (wave & 1) * 64;
    const int lrow = lane >> 3;
    const int lcol = (lane & 7) * 8;

    f4v acc[4][4];
    #pragma unroll
    for (int i = 0; i < 4; i++)
        #pragma unroll
        for (int j = 0; j < 4; j++)
            acc[i][j] = (f4v){0.f, 0.f, 0.f, 0.f};

    for (int k0 = 0; k0 < K; k0 += 64) {
        __syncthreads();
        #pragma unroll
        for (int i = 0; i < 4; i++) {
            int j = wave * 4 + i;
            int row = j * 8 + lrow;
            gl_lds16(A  + (size_t)(m0 + row) * K + k0 + lcol, &As[j * 8][0]);
            gl_lds16(Bt + (size_t)(n0 + row) * K + k0 + lcol, &Bs[j * 8][0]);
        }
        __syncthreads();
        #pragma unroll
        for (int ks = 0; ks < 64; ks += 32) {
            s8v af[4], bfr[4];
            #pragma unroll
            for (int mb = 0; mb < 4; mb++)
                af[mb] = *reinterpret_cast<const s8v*>(&As[wm + mb * 16 + lr][ks + lg * 8]);
            #pragma unroll
            for (int nb = 0; nb < 4; nb++)
                bfr[nb] = *reinterpret_cast<const s8v*>(&Bs[wn + nb * 16 + lr][ks + lg * 8]);
            #pragma unroll
            for (int mb = 0; mb < 4; mb++)
                #pragma unroll
                for (int nb = 0; nb < 4; nb++)
                    acc[mb][nb] = __builtin_amdgcn_mfma_f32_16x16x32_bf16(af[mb], bfr[nb], acc[mb][nb], 0, 0, 0);
        }
    }

    #pragma unroll
    for (int mb = 0; mb < 4; mb++) {
        #pragma unroll
        for (int nb = 0; nb < 4; nb++) {
            int col = n0 + wn + nb * 16 + lr;
            float bv = bias[col];
            #pragma unroll
            for (int r = 0; r < 4; r++) {
                int row = m0 + wm + mb * 16 + lg * 4 + r;
                float val = acc[mb][nb][r] + bv;
                if (OUT_BF16)
                    reinterpret_cast<ushort*>(Cout)[(size_t)row * N + col] = f2bf(val);
                else
                    reinterpret_cast<float*>(Cout)[(size_t)row * N + col] = val;
            }
        }
    }
}

// ---------------- swapped-operand attention tile ----------------
// S^T = K·Q^T via mfma(K,Q): lane owns q = qb+wave*16+lr, s = sb+cb*16+lg*4+r.
// Softmax fully per-lane (15 fmax in-lane + 2 shfl). O^T accumulated via mfma(V^T, P^T).
__device__ __forceinline__ void attn_tile_sw(
    const s8v qf0, const s8v qf1, int q_abs, int qb, int sb,
    int lr, int lg,
    const ushort (*Ks)[72], const ushort (*Vs)[72],
    ushort (*pT)[72],                    // per-wave [16 q][72] scratch
    const float* rel_lds,                // rel_emb * log2e
    float& m, float& l, f4v* oT)
{
    const float SC = 0.125f * 1.44269504f;   // qk-scale * log2e
    f4v sacc[4];
    __builtin_amdgcn_s_setprio(1);
    #pragma unroll
    for (int cb = 0; cb < 4; cb++) {
        sacc[cb] = (f4v){0.f, 0.f, 0.f, 0.f};
        s8v kf0 = *(const s8v*)&Ks[cb * 16 + lr][lg * 8];
        s8v kf1 = *(const s8v*)&Ks[cb * 16 + lr][32 + lg * 8];
        sacc[cb] = __builtin_amdgcn_mfma_f32_16x16x32_bf16(kf0, qf0, sacc[cb], 0, 0, 0);
        sacc[cb] = __builtin_amdgcn_mfma_f32_16x16x32_bf16(kf1, qf1, sacc[cb], 0, 0, 0);
    }
    __builtin_amdgcn_s_setprio(0);

    if (sb + 192 <= qb) {
        // far tile: all rel distances clip to -128 -> uniform bias, no causal mask
        float c = rel_lds[0];
        #pragma unroll
        for (int cb = 0; cb < 4; cb++)
            #pragma unroll
            for (int r = 0; r < 4; r++)
                sacc[cb][r] = sacc[cb][r] * SC + c;
    } else {
        #pragma unroll
        for (int cb = 0; cb < 4; cb++) {
            #pragma unroll
            for (int r = 0; r < 4; r++) {
                int s = sb + cb * 16 + lg * 4 + r;
                int rel = s - q_abs;
                rel = (rel < -128 ? -128 : (rel > 128 ? 128 : rel)) + 128;
                float val = sacc[cb][r] * SC + rel_lds[rel];
                if (s > q_abs) val = -3.0e38f;
                sacc[cb][r] = val;
            }
        }
    }

    // row max: in-lane tree over 16 + 2 shfl across the 4 lg-lanes
    float pm0 = fmaxf(fmaxf(sacc[0][0], sacc[0][1]), fmaxf(sacc[0][2], sacc[0][3]));
    float pm1 = fmaxf(fmaxf(sacc[1][0], sacc[1][1]), fmaxf(sacc[1][2], sacc[1][3]));
    float pm2 = fmaxf(fmaxf(sacc[2][0], sacc[2][1]), fmaxf(sacc[2][2], sacc[2][3]));
    float pm3 = fmaxf(fmaxf(sacc[3][0], sacc[3][1]), fmaxf(sacc[3][2], sacc[3][3]));
    float pm = fmaxf(fmaxf(pm0, pm1), fmaxf(pm2, pm3));
    pm = fmaxf(pm, __shfl_xor(pm, 16, 64));
    pm = fmaxf(pm, __shfl_xor(pm, 32, 64));

    // defer-max (T13): only rescale when the running max grew by > 8 (log2 units)
    if (__any(pm > m + 8.0f)) {
        float mnew = fmaxf(m, pm);
        float alpha = exp2f(m - mnew);
        l *= alpha;
        #pragma unroll
        for (int d = 0; d < 4; d++)
            #pragma unroll
            for (int r = 0; r < 4; r++)
                oT[d][r] *= alpha;
        m = mnew;
    }

    // p = exp2(s - m); in-lane sum + 2 shfl
    float sum = 0.f;
    #pragma unroll
    for (int cb = 0; cb < 4; cb++) {
        #pragma unroll
        for (int r = 0; r < 4; r++) {
            float p = exp2f(sacc[cb][r] - m);
            sacc[cb][r] = p;
            sum += p;
        }
    }
    sum += __shfl_xor(sum, 16, 64);
    sum += __shfl_xor(sum, 32, 64);
    l += sum;

    // pack P^T -> per-wave LDS: pT[q=lr][s], 4 x ds_write_b64
    #pragma unroll
    for (int cb = 0; cb < 4; cb++) {
        unsigned lo = (unsigned)f2bf(sacc[cb][0]) | ((unsigned)f2bf(sacc[cb][1]) << 16);
        unsigned hi = (unsigned)f2bf(sacc[cb][2]) | ((unsigned)f2bf(sacc[cb][3]) << 16);
        *(unsigned long long*)&pT[lr][cb * 16 + lg * 4] =
            (unsigned long long)lo | ((unsigned long long)hi << 32);
    }

    // O^T += V^T · P^T  (A = V^T frag row=d, B = P^T frag col=q)
    __builtin_amdgcn_s_setprio(1);
    #pragma unroll
    for (int ch = 0; ch < 2; ch++) {
        s8v pf = *(const s8v*)&pT[lr][ch * 32 + lg * 8];
        #pragma unroll
        for (int d = 0; d < 4; d++) {
            s8v vf = *(const s8v*)&Vs[d * 16 + lr][ch * 32 + lg * 8];
            oT[d] = __builtin_amdgcn_mfma_f32_16x16x32_bf16(vf, pf, oT[d], 0, 0, 0);
        }
    }
    __builtin_amdgcn_s_setprio(0);
}

// normalize O^T, transpose through per-wave LDS, coalesced store
__device__ __forceinline__ void store_O(
    f4v* oT, float l, int lr, int lg, int lane, int wave,
    ushort (*pT)[72], int qb, size_t rowb, int h, ushort* __restrict__ attn_out)
{
    float inv = 1.0f / l;
    #pragma unroll
    for (int d = 0; d < 4; d++) {
        unsigned lo = (unsigned)f2bf(oT[d][0] * inv) | ((unsigned)f2bf(oT[d][1] * inv) << 16);
        unsigned hi = (unsigned)f2bf(oT[d][2] * inv) | ((unsigned)f2bf(oT[d][3] * inv) << 16);
        *(unsigned long long*)&pT[lr][d * 16 + lg * 4] =
            (unsigned long long)lo | ((unsigned long long)hi << 32);
    }
    int q_r = lane >> 2, part = lane & 3;
    s8v a = *(const s8v*)&pT[q_r][part * 16];
    s8v b = *(const s8v*)&pT[q_r][part * 16 + 8];
    ushort* dst = attn_out + (rowb + qb + wave * 16 + q_r) * 1024 + h * 64 + part * 16;
    *(s8v*)dst = a;
    *(s8v*)(dst + 8) = b;
}

// ---------------- flash attention: one 64-row q-tile per block, LPT dispatch ----------
// Grid 1024 = 32 qtiles x 32 bh. x>>5 ranks tiles heavy-first (qt = 31-(x>>5));
// bh in low 5 bits spreads consecutive blocks across XCDs. HW block scheduler
// backfills light tiles as heavies run -> 4 blocks/CU, balanced makespan.
__global__ __launch_bounds__(256, 4) void attn_kernel(
    const ushort* __restrict__ qkv, const ushort* __restrict__ vt_g,
    const float* __restrict__ rel_emb, ushort* __restrict__ attn_out, int T)
{
    __shared__ ushort Ks[64][72];
    __shared__ ushort Vs[64][72];
    __shared__ ushort p_lds[4][16][72];
    __shared__ float rel_lds[257];

    const int t = threadIdx.x;
    const int x = blockIdx.x;
    const int qt = 31 - (x >> 5);              // heavy tiles first
    const int bh = x & 31;
    const int qb = qt * 64;
    const int b = bh >> 4, h = bh & 15;
    const size_t rowb = (size_t)b * T;

    for (int i = t; i < 257; i += 256) rel_lds[i] = rel_emb[i * 16 + h] * 1.44269504f;

    const int wave = t >> 6, lane = t & 63;
    const int lr = lane & 15, lg = lane >> 4;
    const int sr = t >> 3, sc = (t & 7) * 8;

    const ushort* kbase = qkv + rowb * 3072 + 1024 + h * 64;
    const ushort* vbase = vt_g + (size_t)bh * 64 * T;

    const int qa = qb + wave * 16 + lr;
    const ushort* qptr = qkv + (rowb + qa) * 3072 + h * 64;
    s8v qf0 = *(const s8v*)(qptr + lg * 8);
    s8v qf1 = *(const s8v*)(qptr + 32 + lg * 8);

    float m = -3.0e38f, l = 0.f;
    f4v oT[4];
    #pragma unroll
    for (int d = 0; d < 4; d++) oT[d] = (f4v){0.f, 0.f, 0.f, 0.f};

    const int nt = qt + 1;

    s8v ka0 = *(const s8v*)(kbase + (size_t)sr * 3072 + sc);
    s8v ka1 = *(const s8v*)(kbase + (size_t)(32 + sr) * 3072 + sc);
    s8v va0 = *(const s8v*)(vbase + (size_t)sr * T + sc);
    s8v va1 = *(const s8v*)(vbase + (size_t)(32 + sr) * T + sc);

    for (int st = 0; st < nt; ++st) {
        const int sb = st * 64;
        __syncthreads();
        *(s8v*)&Ks[sr][sc]      = ka0;
        *(s8v*)&Ks[32 + sr][sc] = ka1;
        *(s8v*)&Vs[sr][sc]      = va0;
        *(s8v*)&Vs[32 + sr][sc] = va1;
        __syncthreads();

        if (st + 1 < nt) {
            const int sn = sb + 64;
            ka0 = *(const s8v*)(kbase + (size_t)(sn + sr) * 3072 + sc);
            ka1 = *(const s8v*)(kbase + (size_t)(sn + 32 + sr) * 3072 + sc);
            va0 = *(const s8v*)(vbase + (size_t)sr * T + sn + sc);
            va1 = *(const s8v*)(vbase + (size_t)(32 + sr) * T + sn + sc);
        }

        attn_tile_sw(qf0, qf1, qa, qb, sb, lr, lg, Ks, Vs, p_lds[wave], rel_lds, m, l, oT);
    }

    store_O(oT, l, lr, lg, lane, wave, p_lds[wave], qb, rowb, h, attn_out);
}

extern "C" void kernel_launch(void* const* d_in, const int* in_sizes, int n_in,
                              void* d_out, int out_size, void* d_ws, size_t ws_size,
                              hipStream_t stream) {
    const float* x       = (const float*)d_in[0];   // [B,T,1024]
    const float* Wqkv    = (const float*)d_in[1];   // [1024,3072]
    const float* bqkv    = (const float*)d_in[2];   // [3072]
    const float* Wout    = (const float*)d_in[3];   // [1024,1024]
    const float* bout    = (const float*)d_in[4];   // [1024]
    const float* rel_emb = (const float*)d_in[5];   // [257,16]
    float* out = (float*)d_out;

    const int M = in_sizes[0] / 1024;   // B*T = 4096
    const int T = 2048;
    const int B = M / T;

    ushort* x_bf = (ushort*)d_ws;                        // M*1024 bf16
    ushort* Wq_t = x_bf + (size_t)M * 1024;              // 3072*1024
    ushort* Wo_t = Wq_t + (size_t)3072 * 1024;           // 1024*1024
    ushort* qkv  = Wo_t + (size_t)1024 * 1024;           // M*3072
    ushort* attn = qkv + (size_t)M * 3072;               // M*1024
    ushort* vt_g = attn + (size_t)M * 1024;              // B*16*64*T = M*1024

    hipLaunchKernelGGL(cast_bf16_kernel, dim3((M * 1024 / 4 + 255) / 256), dim3(256), 0, stream,
                       x, x_bf, M * 1024 / 4);
    hipLaunchKernelGGL(transpose_cast_kernel, dim3(3072 / 32, 1024 / 32), dim3(256), 0, stream,
                       Wqkv, Wq_t, 1024, 3072);
    hipLaunchKernelGGL(transpose_cast_kernel, dim3(1024 / 32, 1024 / 32), dim3(256), 0, stream,
                       Wout, Wo_t, 1024, 1024);
    hipLaunchKernelGGL((gemm_bt_kernel<true>), dim3(3072 / 128, M / 128), dim3(256), 0, stream,
                       x_bf, Wq_t, bqkv, (void*)qkv, M, 3072, 1024);
    hipLaunchKernelGGL(vtrans_kernel, dim3(T / 64, B * 16), dim3(256), 0, stream,
                       qkv, vt_g, T);
    hipLaunchKernelGGL(attn_kernel, dim3(32 * B * 16), dim3(256), 0, stream,
                       qkv, vt_g, rel_emb, attn, T);
    hipLaunchKernelGGL((gemm_bt_kernel<false>), dim3(1024 / 128, M / 128), dim3(256), 0, stream,
                       attn, Wo_t, bout, (void*)out, M, 1024, 1024);
}